// Round 8
// baseline (257.322 us; speedup 1.0000x reference)
//
#include <hip/hip_runtime.h>
#include <hip/hip_bf16.h>

typedef unsigned short u16;
typedef unsigned int u32;
typedef __attribute__((ext_vector_type(8))) short short8;
typedef __attribute__((ext_vector_type(4))) float f32x4;
typedef __attribute__((ext_vector_type(2))) unsigned int u32x2;

#define NN 8192
#define FIN 512
#define FOUT 128
#define NEG 0.2f
#define L2E 1.44269504088896340736f
#define EXP2(x) __builtin_amdgcn_exp2f(x)
#define LOG2(x) __builtin_amdgcn_logf(x)

__device__ __forceinline__ u16 f2bf(float f) {
  u32 u = __builtin_bit_cast(u32, f);
  u32 r = (u + 0x7fffu + ((u >> 16) & 1u)) >> 16;
  return (u16)r;
}

// K1: h = x @ w. Emits s,t scores and hb in MFMA-native coalesced layout:
// hb[kgrp][nblk][kg][nlo][e] = bf16(h[kgrp*32 + kg*8 + e][nblk*16 + nlo])
// so pass-B's B-fragment load is base + lane*16B (fully coalesced).
__global__ __launch_bounds__(256) void k_h(const float* __restrict__ x,
                                           const float* __restrict__ w,
                                           const float* __restrict__ av,
                                           u16* __restrict__ hb,
                                           float* __restrict__ sg,
                                           float* __restrict__ tgo) {
  __shared__ float xs[32][68];
  __shared__ float ws_[64][128];
  __shared__ u16 ht[32][130];   // bf16 h tile, padded vs bank conflicts
  const int t = threadIdx.x;
  const int r0 = blockIdx.x * 32;
  const int r = t >> 3;
  const int cq = (t & 7) * 4;
  float acc[4][4] = {};
  for (int kc = 0; kc < FIN; kc += 64) {
    __syncthreads();
    {
      const int rr = t >> 3, cc = (t & 7) * 8;
      const float4* src = (const float4*)(x + (size_t)(r0 + rr) * FIN + kc + cc);
      *(float4*)&xs[rr][cc] = src[0];
      *(float4*)&xs[rr][cc + 4] = src[1];
    }
#pragma unroll
    for (int i = 0; i < 8; ++i) {
      const int off = i * 1024 + t * 4;
      const int wr = off >> 7, wc = off & 127;
      *(float4*)&ws_[wr][wc] = *(const float4*)(w + (size_t)(kc + wr) * FOUT + wc);
    }
    __syncthreads();
    for (int kk = 0; kk < 64; ++kk) {
      const float xv = xs[r][kk];
#pragma unroll
      for (int g = 0; g < 4; ++g) {
        const float4 wv = *(const float4*)&ws_[kk][cq + 32 * g];
        acc[g][0] = fmaf(xv, wv.x, acc[g][0]);
        acc[g][1] = fmaf(xv, wv.y, acc[g][1]);
        acc[g][2] = fmaf(xv, wv.z, acc[g][2]);
        acc[g][3] = fmaf(xv, wv.w, acc[g][3]);
      }
    }
  }
  const int rg = r0 + r;
  float sp = 0.f, tp = 0.f;
#pragma unroll
  for (int g = 0; g < 4; ++g) {
#pragma unroll
    for (int e = 0; e < 4; ++e) {
      const int n = cq + 32 * g + e;
      const float v = acc[g][e];
      ht[r][n] = f2bf(v);
      sp = fmaf(v, av[n], sp);
      tp = fmaf(v, av[FOUT + n], tp);
    }
  }
#pragma unroll
  for (int d = 1; d < 8; d <<= 1) {
    sp += __shfl_xor(sp, d);
    tp += __shfl_xor(tp, d);
  }
  if ((t & 7) == 0) { sg[rg] = sp; tgo[rg] = tp; }
  __syncthreads();
  // transposed coalesced write of the 32-row tile (= kgrp blockIdx.x):
  // linear o = ((nblk*4 + kg)*16 + nlo)*8 + e; row = kg*8+e, col = nblk*16+nlo
  {
    u16* dst = hb + (size_t)blockIdx.x * 4096;
    union { short8 v; u16 us[8]; } b1, b2;
    const int o1 = t * 8;
    const int o2 = 2048 + t * 8;
#pragma unroll
    for (int q = 0; q < 8; ++q) {
      int oo = o1 + q;
      b1.us[q] = ht[((oo >> 7) & 3) * 8 + (oo & 7)][(oo >> 9) * 16 + ((oo >> 3) & 15)];
      oo = o2 + q;
      b2.us[q] = ht[((oo >> 7) & 3) * 8 + (oo & 7)][(oo >> 9) * 16 + ((oo >> 3) & 15)];
    }
    *(short8*)(dst + o1) = b1.v;
    *(short8*)(dst + o2) = b2.v;
  }
}

// K2: tmax = max(t)
__global__ __launch_bounds__(256) void k_tmax(const float* __restrict__ t,
                                              float* __restrict__ tmax) {
  __shared__ float red[256];
  float m = -1e30f;
  for (int i = threadIdx.x; i < NN; i += 256) m = fmaxf(m, t[i]);
  red[threadIdx.x] = m;
  __syncthreads();
  for (int s2 = 128; s2 > 0; s2 >>= 1) {
    if (threadIdx.x < s2) red[threadIdx.x] = fmaxf(red[threadIdx.x], red[threadIdx.x + s2]);
    __syncthreads();
  }
  if (threadIdx.x == 0) tmax[0] = red[0];
}

// K3: fused attention. Block = 16 rows, 1024 thr (16 waves), grid 512,
// 2 blocks/CU (LDS ~41KB, VGPR<=64 -> ~88% occupancy).
// Pass A: wave w streams adj row ONCE -> mask bits + folded constant
// c2 = -(m*log2e + log2 l), m = lrelu(s+tmax) monotone bound.
// Pass B: 32 chunks of 256 cols; per iter: prefetch coalesced hb frags ->
// ONE barrier -> softmax(c+1) (float4 t-load, row-contiguous float4 att
// store, bf16 P double-buffer in LDS) overlapped with MFMA(c).
// 16 waves = 8 colgroups x 2 K-halves; h' merged once via LDS atomicAdd.
__global__ __launch_bounds__(1024, 2) void k_attn(const int* __restrict__ adj,
                                                  const float* __restrict__ sg,
                                                  const float* __restrict__ tg,
                                                  const float* __restrict__ tmaxp,
                                                  const u16* __restrict__ hb,
                                                  float* __restrict__ att,
                                                  float* __restrict__ hp) {
  __shared__ u32 mask[16 * 256];      // 16 KB adj bits
  __shared__ u16 pl[2][16 * 256];     // 16 KB P-tile double buffer
  __shared__ float hsum[16 * 132];    // 8.25 KB h' accumulator
  __shared__ float s_s[16], s_c2[16], s_l[16];
  const int tid = threadIdx.x;
  const int w = tid >> 6, lane = tid & 63;
  const int r0 = blockIdx.x << 4;
  const int row = r0 + w;             // wave w owns this attention row

  for (int i = tid; i < 16 * 132; i += 1024) hsum[i] = 0.f;

  // ---- Pass A ----
  const float sv = sg[row];
  const float vm = sv + tmaxp[0];
  const float m = fmaxf(vm, NEG * vm);
  const float m2 = m * L2E;
  const int4* ap = (const int4*)(adj + (size_t)row * NN);
  float sum = 0.f;
#pragma unroll 4
  for (int it = 0; it < 32; ++it) {
    const int4 a0 = ap[it * 64 + lane];
    const float4 tv = *(const float4*)(tg + it * 256 + lane * 4);
    u32 nib = 0u;
    float e, p, sm = 0.f;
    e = sv + tv.x; e = fmaxf(e, NEG * e); p = EXP2(fmaf(e, L2E, -m2)); sm += (a0.x > 0) ? p : 0.f; nib |= (a0.x > 0) ? 1u : 0u;
    e = sv + tv.y; e = fmaxf(e, NEG * e); p = EXP2(fmaf(e, L2E, -m2)); sm += (a0.y > 0) ? p : 0.f; nib |= (a0.y > 0) ? 2u : 0u;
    e = sv + tv.z; e = fmaxf(e, NEG * e); p = EXP2(fmaf(e, L2E, -m2)); sm += (a0.z > 0) ? p : 0.f; nib |= (a0.z > 0) ? 4u : 0u;
    e = sv + tv.w; e = fmaxf(e, NEG * e); p = EXP2(fmaf(e, L2E, -m2)); sm += (a0.w > 0) ? p : 0.f; nib |= (a0.w > 0) ? 8u : 0u;
    sum += sm;
    u32 v0 = nib;
    v0 |= __shfl_xor(v0, 1) << 4;
    v0 |= __shfl_xor(v0, 2) << 8;
    v0 |= __shfl_xor(v0, 4) << 16;
    if ((lane & 7) == 0) mask[w * 256 + it * 8 + (lane >> 3)] = v0;
  }
#pragma unroll
  for (int d = 1; d < 64; d <<= 1) sum += __shfl_xor(sum, d);
  if (lane == 0) { s_l[w] = sum; s_s[w] = sv; }
  __syncthreads();
  if (tid < 16) {
    const float s2v = s_s[tid] + tmaxp[0];
    const float mm = fmaxf(s2v, NEG * s2v);
    s_c2[tid] = -(mm * L2E + LOG2(s_l[tid]));
  }
  __syncthreads();

  // ---- Pass B ----
  const float sR = s_s[w], c2R = s_c2[w];
  const int swzW = (w & 7) << 3;
  const int arow = lane & 15, kg = lane >> 4;
  const int bcol = 16 * (w & 7) + arow;   // h' output col
  const int ksbase = (w >> 3) * 4;        // this wave's 4 of 8 K-slices/chunk
  const int swzA = (arow & 7) << 3;
  f32x4 acc = {0.f, 0.f, 0.f, 0.f};

#define COMPUTE(c, buf)                                                        \
  {                                                                            \
    const int j0 = (c) << 8;                                                   \
    const int jl = lane * 4;                                                   \
    const float4 tv = *(const float4*)(tg + j0 + jl);                          \
    const u32 wd = mask[w * 256 + (c) * 8 + (lane >> 3)];                      \
    const u32 nib = (wd >> (jl & 31)) & 0xfu;                                  \
    float e0 = sR + tv.x; e0 = fmaxf(e0, NEG * e0);                            \
    float e1 = sR + tv.y; e1 = fmaxf(e1, NEG * e1);                            \
    float e2 = sR + tv.z; e2 = fmaxf(e2, NEG * e2);                            \
    float e3 = sR + tv.w; e3 = fmaxf(e3, NEG * e3);                            \
    const float p0 = (nib & 1u) ? EXP2(fmaf(e0, L2E, c2R)) : 0.f;              \
    const float p1 = (nib & 2u) ? EXP2(fmaf(e1, L2E, c2R)) : 0.f;              \
    const float p2 = (nib & 4u) ? EXP2(fmaf(e2, L2E, c2R)) : 0.f;              \
    const float p3 = (nib & 8u) ? EXP2(fmaf(e3, L2E, c2R)) : 0.f;              \
    float4 o; o.x = p0; o.y = p1; o.z = p2; o.w = p3;                          \
    *(float4*)(att + (size_t)row * NN + j0 + jl) = o;                          \
    u32x2 pk;                                                                  \
    pk.x = (u32)f2bf(p0) | ((u32)f2bf(p1) << 16);                              \
    pk.y = (u32)f2bf(p2) | ((u32)f2bf(p3) << 16);                              \
    *(u32x2*)&pl[buf][w * 256 + (jl ^ swzW)] = pk;                             \
  }

  COMPUTE(0, 0);
  for (int c = 0; c < 32; ++c) {
    // prefetch this chunk's coalesced B-fragments (base + lane*16B)
    const u16* hq = hb + ((size_t)(c * 8 + ksbase)) * 4096 + (w & 7) * 512 + lane * 8;
    const short8 b0 = *(const short8*)(hq);
    const short8 b1 = *(const short8*)(hq + 4096);
    const short8 b2 = *(const short8*)(hq + 8192);
    const short8 b3 = *(const short8*)(hq + 12288);
    __syncthreads();
    if (c < 31) COMPUTE(c + 1, (c + 1) & 1);
    {
      const u16* pb = &pl[c & 1][0];
      const int ko0 = ksbase * 32 + kg * 8;
      const short8 a0 = *(const short8*)(pb + arow * 256 + ((ko0) ^ swzA));
      const short8 a1 = *(const short8*)(pb + arow * 256 + ((ko0 + 32) ^ swzA));
      const short8 a2 = *(const short8*)(pb + arow * 256 + ((ko0 + 64) ^ swzA));
      const short8 a3 = *(const short8*)(pb + arow * 256 + ((ko0 + 96) ^ swzA));
      acc = __builtin_amdgcn_mfma_f32_16x16x32_bf16(a0, b0, acc, 0, 0, 0);
      acc = __builtin_amdgcn_mfma_f32_16x16x32_bf16(a1, b1, acc, 0, 0, 0);
      acc = __builtin_amdgcn_mfma_f32_16x16x32_bf16(a2, b2, acc, 0, 0, 0);
      acc = __builtin_amdgcn_mfma_f32_16x16x32_bf16(a3, b3, acc, 0, 0, 0);
    }
  }
#undef COMPUTE

  // merge the two K-half partials and store h'
#pragma unroll
  for (int q = 0; q < 4; ++q)
    atomicAdd(&hsum[(kg * 4 + q) * 132 + bcol], acc[q]);
  __syncthreads();
  for (int i = tid; i < 2048; i += 1024)
    hp[(size_t)(r0 + (i >> 7)) * FOUT + (i & 127)] = hsum[(i >> 7) * 132 + (i & 127)];
}

extern "C" void kernel_launch(void* const* d_in, const int* in_sizes, int n_in,
                              void* d_out, int out_size, void* d_ws, size_t ws_size,
                              hipStream_t stream) {
  const float* x = (const float*)d_in[0];
  const int* adj = (const int*)d_in[1];
  const float* w = (const float*)d_in[2];
  const float* a = (const float*)d_in[3];
  float* out = (float*)d_out;
  float* att = out;
  float* hp = out + (size_t)NN * NN;
  u16* hb = (u16*)d_ws;                                        // [0, 2MB)
  float* s = (float*)((char*)d_ws + (size_t)2 * 1024 * 1024);
  float* t = s + NN;
  float* tmax = t + NN;

  k_h<<<256, 256, 0, stream>>>(x, w, a, hb, s, t);
  k_tmax<<<1, 256, 0, stream>>>(t, tmax);
  k_attn<<<512, 1024, 0, stream>>>(adj, s, t, tmax, hb, att, hp);
}

// Round 10
// 204.666 us; speedup vs baseline: 1.2573x; 1.2573x over previous
//
#include <hip/hip_runtime.h>
#include <hip/hip_bf16.h>

typedef unsigned short u16;
typedef unsigned int u32;
typedef __attribute__((ext_vector_type(8))) short short8;
typedef __attribute__((ext_vector_type(4))) float f32x4;
typedef __attribute__((ext_vector_type(2))) unsigned int u32x2;

#define NN 8192
#define FIN 512
#define FOUT 128
#define NEG 0.2f
#define L2E 1.44269504088896340736f
#define EXP2(x) __builtin_amdgcn_exp2f(x)
#define LOG2(x) __builtin_amdgcn_logf(x)

__device__ __forceinline__ u16 f2bf(float f) {
  u32 u = __builtin_bit_cast(u32, f);
  u32 r = (u + 0x7fffu + ((u >> 16) & 1u)) >> 16;
  return (u16)r;
}

// K1: h = x @ w. Emits s,t scores and hb in MFMA-native coalesced layout:
// hb[kgrp][nblk][kg][nlo][e] = bf16(h[kgrp*32 + kg*8 + e][nblk*16 + nlo]).
__global__ __launch_bounds__(256) void k_h(const float* __restrict__ x,
                                           const float* __restrict__ w,
                                           const float* __restrict__ av,
                                           u16* __restrict__ hb,
                                           float* __restrict__ sg,
                                           float* __restrict__ tgo) {
  __shared__ float xs[32][68];
  __shared__ float ws_[64][128];
  __shared__ u16 ht[32][130];
  const int t = threadIdx.x;
  const int r0 = blockIdx.x * 32;
  const int r = t >> 3;
  const int cq = (t & 7) * 4;
  float acc[4][4] = {};
  for (int kc = 0; kc < FIN; kc += 64) {
    __syncthreads();
    {
      const int rr = t >> 3, cc = (t & 7) * 8;
      const float4* src = (const float4*)(x + (size_t)(r0 + rr) * FIN + kc + cc);
      *(float4*)&xs[rr][cc] = src[0];
      *(float4*)&xs[rr][cc + 4] = src[1];
    }
#pragma unroll
    for (int i = 0; i < 8; ++i) {
      const int off = i * 1024 + t * 4;
      const int wr = off >> 7, wc = off & 127;
      *(float4*)&ws_[wr][wc] = *(const float4*)(w + (size_t)(kc + wr) * FOUT + wc);
    }
    __syncthreads();
    for (int kk = 0; kk < 64; ++kk) {
      const float xv = xs[r][kk];
#pragma unroll
      for (int g = 0; g < 4; ++g) {
        const float4 wv = *(const float4*)&ws_[kk][cq + 32 * g];
        acc[g][0] = fmaf(xv, wv.x, acc[g][0]);
        acc[g][1] = fmaf(xv, wv.y, acc[g][1]);
        acc[g][2] = fmaf(xv, wv.z, acc[g][2]);
        acc[g][3] = fmaf(xv, wv.w, acc[g][3]);
      }
    }
  }
  const int rg = r0 + r;
  float sp = 0.f, tp = 0.f;
#pragma unroll
  for (int g = 0; g < 4; ++g) {
#pragma unroll
    for (int e = 0; e < 4; ++e) {
      const int n = cq + 32 * g + e;
      const float v = acc[g][e];
      ht[r][n] = f2bf(v);
      sp = fmaf(v, av[n], sp);
      tp = fmaf(v, av[FOUT + n], tp);
    }
  }
#pragma unroll
  for (int d = 1; d < 8; d <<= 1) {
    sp += __shfl_xor(sp, d);
    tp += __shfl_xor(tp, d);
  }
  if ((t & 7) == 0) { sg[rg] = sp; tgo[rg] = tp; }
  __syncthreads();
  {
    u16* dst = hb + (size_t)blockIdx.x * 4096;
    union { short8 v; u16 us[8]; } b1, b2;
    const int o1 = t * 8;
    const int o2 = 2048 + t * 8;
#pragma unroll
    for (int q = 0; q < 8; ++q) {
      int oo = o1 + q;
      b1.us[q] = ht[((oo >> 7) & 3) * 8 + (oo & 7)][(oo >> 9) * 16 + ((oo >> 3) & 15)];
      oo = o2 + q;
      b2.us[q] = ht[((oo >> 7) & 3) * 8 + (oo & 7)][(oo >> 9) * 16 + ((oo >> 3) & 15)];
    }
    *(short8*)(dst + o1) = b1.v;
    *(short8*)(dst + o2) = b2.v;
  }
}

// K2: tmax = max(t)
__global__ __launch_bounds__(256) void k_tmax(const float* __restrict__ t,
                                              float* __restrict__ tmax) {
  __shared__ float red[256];
  float m = -1e30f;
  for (int i = threadIdx.x; i < NN; i += 256) m = fmaxf(m, t[i]);
  red[threadIdx.x] = m;
  __syncthreads();
  for (int s2 = 128; s2 > 0; s2 >>= 1) {
    if (threadIdx.x < s2) red[threadIdx.x] = fmaxf(red[threadIdx.x], red[threadIdx.x + s2]);
    __syncthreads();
  }
  if (threadIdx.x == 0) tmax[0] = red[0];
}

// K3: fused attention. Block = 16 rows, 512 thr (8 waves),
// __launch_bounds__(512,4) -> 128-VGPR budget so prefetch stays in registers.
// Pass A: wave w streams adj rows 2w,2w+1 ONCE -> mask bits + denoms.
// Pass B: 16 chunks of 512 cols; per iter ONE barrier; interleave
// 4x(hb prefetch quad) with 2 softmax quads (2 rows share t-loads) and
// 4 MFMA groups. Wave owns full K for its column-group -> direct h' store.
__global__ __launch_bounds__(512, 4) void k_attn(const int* __restrict__ adj,
                                                 const float* __restrict__ sg,
                                                 const float* __restrict__ tg,
                                                 const float* __restrict__ tmaxp,
                                                 const u16* __restrict__ hb,
                                                 float* __restrict__ att,
                                                 float* __restrict__ hp) {
  __shared__ u32 mask[16 * 256];    // 16 KB adj bits
  __shared__ u16 pl[2][16][512];    // 32 KB P double buffer
  __shared__ float s_c2[16], s_l[16];
  const int tid = threadIdx.x;
  const int w = tid >> 6, lane = tid & 63;
  const int r0 = blockIdx.x << 4;
  const int rA = 2 * w, rB = rA + 1;

  // ---- Pass A ----
  const float tmx = tmaxp[0];
  const float sA = sg[r0 + rA], sB = sg[r0 + rB];
  const float vA = sA + tmx, vB = sB + tmx;
  const float mA2 = fmaxf(vA, NEG * vA) * L2E;
  const float mB2 = fmaxf(vB, NEG * vB) * L2E;
  const int4* adjA = (const int4*)(adj + (size_t)(r0 + rA) * NN);
  const int4* adjB = (const int4*)(adj + (size_t)(r0 + rB) * NN);
  float sum0 = 0.f, sum1 = 0.f;
#pragma unroll 4
  for (int it = 0; it < 32; ++it) {
    const int4 a0 = adjA[it * 64 + lane];
    const int4 a1 = adjB[it * 64 + lane];
    const float4 tv = *(const float4*)(tg + it * 256 + lane * 4);
    u32 nib0 = 0u, nib1 = 0u;
    {
      float e, p, sm = 0.f;
      e = sA + tv.x; e = fmaxf(e, NEG * e); p = EXP2(fmaf(e, L2E, -mA2)); sm += (a0.x > 0) ? p : 0.f; nib0 |= (a0.x > 0) ? 1u : 0u;
      e = sA + tv.y; e = fmaxf(e, NEG * e); p = EXP2(fmaf(e, L2E, -mA2)); sm += (a0.y > 0) ? p : 0.f; nib0 |= (a0.y > 0) ? 2u : 0u;
      e = sA + tv.z; e = fmaxf(e, NEG * e); p = EXP2(fmaf(e, L2E, -mA2)); sm += (a0.z > 0) ? p : 0.f; nib0 |= (a0.z > 0) ? 4u : 0u;
      e = sA + tv.w; e = fmaxf(e, NEG * e); p = EXP2(fmaf(e, L2E, -mA2)); sm += (a0.w > 0) ? p : 0.f; nib0 |= (a0.w > 0) ? 8u : 0u;
      sum0 += sm;
    }
    {
      float e, p, sm = 0.f;
      e = sB + tv.x; e = fmaxf(e, NEG * e); p = EXP2(fmaf(e, L2E, -mB2)); sm += (a1.x > 0) ? p : 0.f; nib1 |= (a1.x > 0) ? 1u : 0u;
      e = sB + tv.y; e = fmaxf(e, NEG * e); p = EXP2(fmaf(e, L2E, -mB2)); sm += (a1.y > 0) ? p : 0.f; nib1 |= (a1.y > 0) ? 2u : 0u;
      e = sB + tv.z; e = fmaxf(e, NEG * e); p = EXP2(fmaf(e, L2E, -mB2)); sm += (a1.z > 0) ? p : 0.f; nib1 |= (a1.z > 0) ? 4u : 0u;
      e = sB + tv.w; e = fmaxf(e, NEG * e); p = EXP2(fmaf(e, L2E, -mB2)); sm += (a1.w > 0) ? p : 0.f; nib1 |= (a1.w > 0) ? 8u : 0u;
      sum1 += sm;
    }
    u32 v0 = nib0;
    v0 |= __shfl_xor(v0, 1) << 4;
    v0 |= __shfl_xor(v0, 2) << 8;
    v0 |= __shfl_xor(v0, 4) << 16;
    u32 v1 = nib1;
    v1 |= __shfl_xor(v1, 1) << 4;
    v1 |= __shfl_xor(v1, 2) << 8;
    v1 |= __shfl_xor(v1, 4) << 16;
    if ((lane & 7) == 0) {
      mask[rA * 256 + it * 8 + (lane >> 3)] = v0;
      mask[rB * 256 + it * 8 + (lane >> 3)] = v1;
    }
  }
#pragma unroll
  for (int d = 1; d < 64; d <<= 1) {
    sum0 += __shfl_xor(sum0, d);
    sum1 += __shfl_xor(sum1, d);
  }
  if (lane == 0) { s_l[rA] = sum0; s_l[rB] = sum1; }
  __syncthreads();
  if (tid < 16) {
    const float sv = sg[r0 + tid];
    const float vv = sv + tmx;
    const float mm2 = fmaxf(vv, NEG * vv) * L2E;
    s_c2[tid] = -(mm2 + LOG2(s_l[tid]));
  }
  __syncthreads();

  // ---- Pass B ----
  const float c2A = s_c2[rA], c2B = s_c2[rB];
  const int arow = lane & 15, kg = lane >> 4;
  const int swzA = (arow & 7) << 3;
  const int swzRA = (rA & 7) << 3, swzRB = (rB & 7) << 3;
  f32x4 acc = {0.f, 0.f, 0.f, 0.f};

#define PQUAD(c, buf, q)                                                       \
  {                                                                            \
    const int jq = ((c) << 9) + (q) * 256 + lane * 4;                          \
    const float4 tv = *(const float4*)(tg + jq);                               \
    const u32 wdA = mask[rA * 256 + (jq >> 5)];                                \
    const u32 wdB = mask[rB * 256 + (jq >> 5)];                                \
    const u32 sh = jq & 31;                                                    \
    const u32 nA = (wdA >> sh) & 0xfu;                                         \
    const u32 nB = (wdB >> sh) & 0xfu;                                         \
    float e0, e1, e2, e3;                                                      \
    e0 = sA + tv.x; e0 = fmaxf(e0, NEG * e0);                                  \
    e1 = sA + tv.y; e1 = fmaxf(e1, NEG * e1);                                  \
    e2 = sA + tv.z; e2 = fmaxf(e2, NEG * e2);                                  \
    e3 = sA + tv.w; e3 = fmaxf(e3, NEG * e3);                                  \
    const float pa0 = (nA & 1u) ? EXP2(fmaf(e0, L2E, c2A)) : 0.f;              \
    const float pa1 = (nA & 2u) ? EXP2(fmaf(e1, L2E, c2A)) : 0.f;              \
    const float pa2 = (nA & 4u) ? EXP2(fmaf(e2, L2E, c2A)) : 0.f;              \
    const float pa3 = (nA & 8u) ? EXP2(fmaf(e3, L2E, c2A)) : 0.f;              \
    f32x4 oA = {pa0, pa1, pa2, pa3};                                           \
    __builtin_nontemporal_store(oA, (f32x4*)(att + (size_t)(r0 + rA) * NN + jq)); \
    u32x2 ka;                                                                  \
    ka.x = (u32)f2bf(pa0) | ((u32)f2bf(pa1) << 16);                            \
    ka.y = (u32)f2bf(pa2) | ((u32)f2bf(pa3) << 16);                            \
    *(u32x2*)&pl[buf][rA][((q) * 256 + lane * 4) ^ swzRA] = ka;                \
    e0 = sB + tv.x; e0 = fmaxf(e0, NEG * e0);                                  \
    e1 = sB + tv.y; e1 = fmaxf(e1, NEG * e1);                                  \
    e2 = sB + tv.z; e2 = fmaxf(e2, NEG * e2);                                  \
    e3 = sB + tv.w; e3 = fmaxf(e3, NEG * e3);                                  \
    const float pb0 = (nB & 1u) ? EXP2(fmaf(e0, L2E, c2B)) : 0.f;              \
    const float pb1 = (nB & 2u) ? EXP2(fmaf(e1, L2E, c2B)) : 0.f;              \
    const float pb2 = (nB & 4u) ? EXP2(fmaf(e2, L2E, c2B)) : 0.f;              \
    const float pb3 = (nB & 8u) ? EXP2(fmaf(e3, L2E, c2B)) : 0.f;              \
    f32x4 oB = {pb0, pb1, pb2, pb3};                                           \
    __builtin_nontemporal_store(oB, (f32x4*)(att + (size_t)(r0 + rB) * NN + jq)); \
    u32x2 kb;                                                                  \
    kb.x = (u32)f2bf(pb0) | ((u32)f2bf(pb1) << 16);                            \
    kb.y = (u32)f2bf(pb2) | ((u32)f2bf(pb3) << 16);                            \
    *(u32x2*)&pl[buf][rB][((q) * 256 + lane * 4) ^ swzRB] = kb;                \
  }

#define HBLD(c, g, d0, d1, d2, d3)                                             \
  {                                                                            \
    const u16* hq = hb + ((size_t)((c) * 16 + (g) * 4)) * 4096 + w * 512 + lane * 8; \
    d0 = *(const short8*)(hq);                                                 \
    d1 = *(const short8*)(hq + 4096);                                          \
    d2 = *(const short8*)(hq + 8192);                                          \
    d3 = *(const short8*)(hq + 12288);                                         \
  }

#define MFMAG(c, g, d0, d1, d2, d3)                                            \
  {                                                                            \
    const u16* pr = &pl[(c) & 1][arow][0];                                     \
    const short8 a0 = *(const short8*)(pr + (((g) * 128 + 0 + kg * 8) ^ swzA));   \
    const short8 a1 = *(const short8*)(pr + (((g) * 128 + 32 + kg * 8) ^ swzA));  \
    const short8 a2 = *(const short8*)(pr + (((g) * 128 + 64 + kg * 8) ^ swzA));  \
    const short8 a3 = *(const short8*)(pr + (((g) * 128 + 96 + kg * 8) ^ swzA));  \
    acc = __builtin_amdgcn_mfma_f32_16x16x32_bf16(a0, d0, acc, 0, 0, 0);       \
    acc = __builtin_amdgcn_mfma_f32_16x16x32_bf16(a1, d1, acc, 0, 0, 0);       \
    acc = __builtin_amdgcn_mfma_f32_16x16x32_bf16(a2, d2, acc, 0, 0, 0);       \
    acc = __builtin_amdgcn_mfma_f32_16x16x32_bf16(a3, d3, acc, 0, 0, 0);       \
  }

  short8 b0, b1, b2, b3, d0, d1, d2, d3;
  PQUAD(0, 0, 0);
  PQUAD(0, 0, 1);
  for (int c = 0; c < 16; ++c) {
    HBLD(c, 0, b0, b1, b2, b3);
    __syncthreads();
    HBLD(c, 1, d0, d1, d2, d3);
    if (c < 15) PQUAD(c + 1, (c + 1) & 1, 0);
    MFMAG(c, 0, b0, b1, b2, b3);
    HBLD(c, 2, b0, b1, b2, b3);
    if (c < 15) PQUAD(c + 1, (c + 1) & 1, 1);
    MFMAG(c, 1, d0, d1, d2, d3);
    HBLD(c, 3, d0, d1, d2, d3);
    MFMAG(c, 2, b0, b1, b2, b3);
    MFMAG(c, 3, d0, d1, d2, d3);
  }
#undef PQUAD
#undef HBLD
#undef MFMAG

  const int bcol = w * 16 + arow;
#pragma unroll
  for (int q = 0; q < 4; ++q)
    hp[(size_t)(r0 + kg * 4 + q) * FOUT + bcol] = acc[q];
}

extern "C" void kernel_launch(void* const* d_in, const int* in_sizes, int n_in,
                              void* d_out, int out_size, void* d_ws, size_t ws_size,
                              hipStream_t stream) {
  const float* x = (const float*)d_in[0];
  const int* adj = (const int*)d_in[1];
  const float* w = (const float*)d_in[2];
  const float* a = (const float*)d_in[3];
  float* out = (float*)d_out;
  float* att = out;
  float* hp = out + (size_t)NN * NN;
  u16* hb = (u16*)d_ws;                                        // [0, 2MB)
  float* s = (float*)((char*)d_ws + (size_t)2 * 1024 * 1024);
  float* t = s + NN;
  float* tmax = t + NN;

  k_h<<<256, 256, 0, stream>>>(x, w, a, hb, s, t);
  k_tmax<<<1, 256, 0, stream>>>(t, tmax);
  k_attn<<<512, 512, 0, stream>>>(adj, s, t, tmax, hb, att, hp);
}